// Round 14
// baseline (44.369 us; speedup 1.0000x reference)
//
#include <hip/hip_runtime.h>
#include <hip/hip_bf16.h>
#include <float.h>

// RandomAugment: out = concat(p, where(dist(s, p) > 1, s, 0))
//   d2[m][n] = s2[m] + p2[n] - 2 s_m . p_n   via mfma_f32_32x32x16_bf16
// K=16 carries a 2-term bf16 hi/lo split (only s_lo*p_lo dropped, err<=1.5e-3);
// borderline samples (|d2_q-1|<=1e-2) get an exact in-block rescan with the
// bit-validated fmaf chain -> mask decisions match numpy exactly.
//
// R14: R13 + explicit depth-4 A-tile prefetch. Evidence: R13 VGPR_Count=32
// (compiler allocated ZERO prefetch depth; every A-load's ~300cy L2 latency
// exposed per 4-MFMA group), VALUBusy ~40% across all shapes while traffic
// halving (R13 vs R10) changed nothing -> latency-bound, not BW-bound.
// Named buffers a0..a3 (static indices only, rule #20), load-next-before-
// consume-current, group-of-4 fully unrolled: >=3*(4 MFMA + 32 fold) cycles
// between load issue and use.

typedef __attribute__((ext_vector_type(8))) short short8;
typedef __attribute__((ext_vector_type(16))) float float16;

constexpr float MARGIN = 1e-2f;
constexpr int WV = 16;     // waves per dist block (1024 threads)
constexpr int SPBLK = 128; // samples per block (4 B fragments)

__device__ __forceinline__ unsigned short f2bf(float f) {
  unsigned u = __float_as_uint(f);
  unsigned r = (u + 0x7FFFu + ((u >> 16) & 1u)) >> 16;  // RNE
  return (unsigned short)r;
}
__device__ __forceinline__ float bf2f(unsigned short b) {
  return __uint_as_float(((unsigned)b) << 16);
}

__global__ __launch_bounds__(256) void prep_kernel(
    const float* __restrict__ p, int N,
    float* __restrict__ out, float4* __restrict__ P4, float* __restrict__ mmx,
    short8* __restrict__ Ap) {
  const int tid = threadIdx.x;
  if (blockIdx.x == 0) {
    float mn0 = FLT_MAX, mn1 = FLT_MAX, mn2 = FLT_MAX;
    float mx0 = -FLT_MAX, mx1 = -FLT_MAX, mx2 = -FLT_MAX;
    for (int j = tid; j < N; j += 256) {
      float x = p[3 * j], y = p[3 * j + 1], z = p[3 * j + 2];
      mn0 = fminf(mn0, x); mx0 = fmaxf(mx0, x);
      mn1 = fminf(mn1, y); mx1 = fmaxf(mx1, y);
      mn2 = fminf(mn2, z); mx2 = fmaxf(mx2, z);
    }
    for (int off = 32; off; off >>= 1) {
      mn0 = fminf(mn0, __shfl_xor(mn0, off));
      mn1 = fminf(mn1, __shfl_xor(mn1, off));
      mn2 = fminf(mn2, __shfl_xor(mn2, off));
      mx0 = fmaxf(mx0, __shfl_xor(mx0, off));
      mx1 = fmaxf(mx1, __shfl_xor(mx1, off));
      mx2 = fmaxf(mx2, __shfl_xor(mx2, off));
    }
    __shared__ float smn[4][3], smx[4][3];
    const int w = tid >> 6;
    if ((tid & 63) == 0) {
      smn[w][0] = mn0; smn[w][1] = mn1; smn[w][2] = mn2;
      smx[w][0] = mx0; smx[w][1] = mx1; smx[w][2] = mx2;
    }
    __syncthreads();
    if (tid == 0) {
      for (int k = 0; k < 3; ++k) {
        float a = smn[0][k], b = smx[0][k];
        for (int w2 = 1; w2 < 4; ++w2) {
          a = fminf(a, smn[w2][k]);
          b = fmaxf(b, smx[w2][k]);
        }
        mmx[k] = a;       // mm
        mmx[3 + k] = b;   // mx
      }
    }
  } else {
    const int j = (blockIdx.x - 1) * 256 + tid;   // one point per thread
    if (j < N) {
      float x = p[3 * j], y = p[3 * j + 1], z = p[3 * j + 2];
      out[3 * j] = x; out[3 * j + 1] = y; out[3 * j + 2] = z;
      float n2 = __fadd_rn(__fadd_rn(__fmul_rn(x, x), __fmul_rn(y, y)),
                           __fmul_rn(z, z));
      P4[j] = make_float4(x, y, z, n2);

      // ---- A-fragment packing (split bf16) ----
      unsigned short hx = f2bf(x), hy = f2bf(y), hz = f2bf(z);
      unsigned short lx = f2bf(x - bf2f(hx));
      unsigned short ly = f2bf(y - bf2f(hy));
      unsigned short lz = f2bf(z - bf2f(hz));
      unsigned short p2h = f2bf(n2);
      unsigned short p2l = f2bf(n2 - bf2f(p2h));
      const unsigned short one = 0x3F80;

      const int tile = j >> 5, r = j & 31;
      short8 h0, h1;
      // lanes 0-31 (k0-7): [p_hi x3, p_lo x3, p_hi x,y]
      h0[0] = (short)hx; h0[1] = (short)hy; h0[2] = (short)hz;
      h0[3] = (short)lx; h0[4] = (short)ly; h0[5] = (short)lz;
      h0[6] = (short)hx; h0[7] = (short)hy;
      // lanes 32-63 (k8-15): [p_hi z, 1, 1, p2_h, p2_l, 0, 0, 0]
      h1[0] = (short)hz; h1[1] = (short)one; h1[2] = (short)one;
      h1[3] = (short)p2h; h1[4] = (short)p2l;
      h1[5] = 0; h1[6] = 0; h1[7] = 0;
      Ap[tile * 64 + r] = h0;
      Ap[tile * 64 + 32 + r] = h1;
    }
  }
}

// fold 16 C values + running min via min3-shaped nests (clang -> v_min3_f32)
__device__ __forceinline__ float min16r(float16 c, float run) {
  float t0 = fminf(fminf(c[0], c[1]), c[2]);
  float t1 = fminf(fminf(c[3], c[4]), c[5]);
  float t2 = fminf(fminf(c[6], c[7]), c[8]);
  float t3 = fminf(fminf(c[9], c[10]), c[11]);
  float t4 = fminf(fminf(c[12], c[13]), c[14]);
  float u0 = fminf(fminf(t0, t1), c[15]);
  float u1 = fminf(fminf(t2, t3), t4);
  return fminf(fminf(run, u0), u1);
}

__global__ __launch_bounds__(64 * WV, 4) void dist_kernel(
    const float* __restrict__ u, int M, int N,
    const float4* __restrict__ P4, const float* __restrict__ mmx,
    const short8* __restrict__ Ap, float* __restrict__ out) {
  const int tid = threadIdx.x;
  const int lane = tid & 63;
  const int wv = tid >> 6;
  const int sbase = blockIdx.x * SPBLK;

  const float mm0 = mmx[0], mm1 = mmx[1], mm2 = mmx[2];
  const float r0v = __fsub_rn(mmx[3], mm0);
  const float r1v = __fsub_rn(mmx[4], mm1);
  const float r2v = __fsub_rn(mmx[5], mm2);

  // ---- build 4 B fragments (samples sbase+f*32+(lane&31)) ----
  short8 B[4];
  const bool hi = lane >= 32;
#pragma unroll
  for (int f = 0; f < 4; ++f) {
    int sc = min(sbase + f * 32 + (lane & 31), M - 1);
    float sx = __fadd_rn(__fmul_rn(u[3 * sc], r0v), mm0);
    float sy = __fadd_rn(__fmul_rn(u[3 * sc + 1], r1v), mm1);
    float sz = __fadd_rn(__fmul_rn(u[3 * sc + 2], r2v), mm2);
    float s2 = __fadd_rn(
        __fadd_rn(__fmul_rn(sx, sx), __fmul_rn(sy, sy)), __fmul_rn(sz, sz));
    unsigned short shx = f2bf(sx), shy = f2bf(sy), shz = f2bf(sz);
    unsigned short slx = f2bf(sx - bf2f(shx));
    unsigned short sly = f2bf(sy - bf2f(shy));
    unsigned short slz = f2bf(sz - bf2f(shz));
    unsigned short n2shx = f2bf(-2.0f * bf2f(shx));
    unsigned short n2shy = f2bf(-2.0f * bf2f(shy));
    unsigned short n2shz = f2bf(-2.0f * bf2f(shz));
    unsigned short n2slx = f2bf(-2.0f * bf2f(slx));
    unsigned short n2sly = f2bf(-2.0f * bf2f(sly));
    unsigned short n2slz = f2bf(-2.0f * bf2f(slz));
    unsigned short s2h = f2bf(s2);
    unsigned short s2l = f2bf(s2 - bf2f(s2h));
    const unsigned short one = 0x3F80;
    short8 b;
    b[0] = (short)(hi ? n2slz : n2shx);
    b[1] = (short)(hi ? s2h : n2shy);
    b[2] = (short)(hi ? s2l : n2shz);
    b[3] = (short)(hi ? one : n2shx);
    b[4] = (short)(hi ? one : n2shy);
    b[5] = (short)(hi ? 0 : n2shz);
    b[6] = (short)(hi ? 0 : n2slx);
    b[7] = (short)(hi ? 0 : n2sly);
    B[f] = b;
  }

  // ---- MFMA over this wave's point tiles: depth-4 explicit pipeline ----
  const int NT = N >> 5;            // 256 tiles
  const int TPW = NT / WV;          // 16 tiles per wave
  const short8* __restrict__ ap = Ap + (wv * TPW) * 64 + lane;
  const float16 cz = (float16)0.0f;

  float run0 = FLT_MAX, run1 = FLT_MAX, run2 = FLT_MAX, run3 = FLT_MAX;

#define CONSUME(areg)                                                          \
  {                                                                            \
    float16 c0 = __builtin_amdgcn_mfma_f32_32x32x16_bf16(areg, B[0], cz, 0, 0, 0); \
    run0 = min16r(c0, run0);                                                   \
    float16 c1 = __builtin_amdgcn_mfma_f32_32x32x16_bf16(areg, B[1], cz, 0, 0, 0); \
    run1 = min16r(c1, run1);                                                   \
    float16 c2 = __builtin_amdgcn_mfma_f32_32x32x16_bf16(areg, B[2], cz, 0, 0, 0); \
    run2 = min16r(c2, run2);                                                   \
    float16 c3 = __builtin_amdgcn_mfma_f32_32x32x16_bf16(areg, B[3], cz, 0, 0, 0); \
    run3 = min16r(c3, run3);                                                   \
  }

  short8 a0 = ap[0 * 64];
  short8 a1 = ap[1 * 64];
  short8 a2 = ap[2 * 64];
  short8 a3 = ap[3 * 64];
#pragma unroll 1
  for (int it = 0; it < TPW; it += 4) {
    // refill index: last group re-reads its own tiles (never consumed twice;
    // just keeps addresses in-bounds without a branch)
    const int nx = (it + 4 < TPW) ? it + 4 : it;
    short8 n0 = ap[(nx + 0) * 64];
    CONSUME(a0); a0 = n0;
    short8 n1 = ap[(nx + 1) * 64];
    CONSUME(a1); a1 = n1;
    short8 n2_ = ap[(nx + 2) * 64];
    CONSUME(a2); a2 = n2_;
    short8 n3 = ap[(nx + 3) * 64];
    CONSUME(a3); a3 = n3;
  }
#undef CONSUME

  // rows fully covered by reg-fold + xor32 (layout-proof)
  run0 = fminf(run0, __shfl_xor(run0, 32));
  run1 = fminf(run1, __shfl_xor(run1, 32));
  run2 = fminf(run2, __shfl_xor(run2, 32));
  run3 = fminf(run3, __shfl_xor(run3, 32));

  __shared__ float part[WV][SPBLK];
  {
    const int l31 = lane & 31;
    part[wv][0 * 32 + l31] = run0;   // both half-waves write identical values
    part[wv][1 * 32 + l31] = run1;
    part[wv][2 * 32 + l31] = run2;
    part[wv][3 * 32 + l31] = run3;
  }

  __shared__ float s_sx[SPBLK], s_sy[SPBLK], s_sz[SPBLK], s_s2[SPBLK];
  __shared__ int s_keep[SPBLK];
  __shared__ int s_bl[SPBLK];
  __shared__ int s_nbl;
  __shared__ float s_red[WV];
  if (tid == 0) s_nbl = 0;
  __syncthreads();

  // ---- per-sample: approx decision + borderline detection ----
  if (tid < SPBLK && sbase + tid < M) {
    int sc = sbase + tid;
    float sx = __fadd_rn(__fmul_rn(u[3 * sc], r0v), mm0);
    float sy = __fadd_rn(__fmul_rn(u[3 * sc + 1], r1v), mm1);
    float sz = __fadd_rn(__fmul_rn(u[3 * sc + 2], r2v), mm2);
    float s2 = __fadd_rn(
        __fadd_rn(__fmul_rn(sx, sx), __fmul_rn(sy, sy)), __fmul_rn(sz, sz));
    s_sx[tid] = sx; s_sy[tid] = sy; s_sz[tid] = sz; s_s2[tid] = s2;
    float q = part[0][tid];
#pragma unroll
    for (int w = 1; w < WV; ++w) q = fminf(q, part[w][tid]);
    s_keep[tid] = q > 1.0f;
    if (fabsf(q - 1.0f) <= MARGIN) {
      int idx = atomicAdd(&s_nbl, 1);
      s_bl[idx] = tid;
    }
  }
  __syncthreads();

  // ---- exact rescan of borderline samples (bit-validated fmaf chain) ----
  const int nbl = s_nbl;
  for (int i = 0; i < nbl; ++i) {
    const int t = s_bl[i];
    const float m2x = -2.0f * s_sx[t];
    const float m2y = -2.0f * s_sy[t];
    const float m2z = -2.0f * s_sz[t];
    float dm = FLT_MAX;
    for (int j = tid; j < N; j += 64 * WV) {
      float4 qq = P4[j];
      float tt = fmaf(m2x, qq.x, fmaf(m2y, qq.y, fmaf(m2z, qq.z, qq.w)));
      dm = fminf(dm, tt);
    }
    dm = fminf(dm, __shfl_xor(dm, 1));
    dm = fminf(dm, __shfl_xor(dm, 2));
    dm = fminf(dm, __shfl_xor(dm, 4));
    dm = fminf(dm, __shfl_xor(dm, 8));
    dm = fminf(dm, __shfl_xor(dm, 16));
    dm = fminf(dm, __shfl_xor(dm, 32));
    if (lane == 0) s_red[wv] = dm;
    __syncthreads();
    if (tid == 0) {
      float d = s_red[0];
#pragma unroll
      for (int w = 1; w < WV; ++w) d = fminf(d, s_red[w]);
      float d2 = __fadd_rn(s_s2[t], d);
      float dist = sqrtf(fmaxf(d2, 0.0f));
      s_keep[t] = dist > 1.0f;
    }
    __syncthreads();
  }

  // ---- write masked samples ----
  if (tid < SPBLK && sbase + tid < M) {
    const bool keep = s_keep[tid] != 0;
    float* o = out + (size_t)(N + sbase + tid) * 3;
    o[0] = keep ? s_sx[tid] : 0.0f;
    o[1] = keep ? s_sy[tid] : 0.0f;
    o[2] = keep ? s_sz[tid] : 0.0f;
  }
}

extern "C" void kernel_launch(void* const* d_in, const int* in_sizes, int n_in,
                              void* d_out, int out_size, void* d_ws, size_t ws_size,
                              hipStream_t stream) {
  const float* p = (const float*)d_in[0];
  const float* u = (const float*)d_in[1];
  const int N = in_sizes[0] / 3;   // 8192
  const int M = in_sizes[1] / 3;   // 32768
  float* out = (float*)d_out;

  float* mmx = (float*)d_ws;                             // 6 floats @ 0
  float4* P4 = (float4*)((char*)d_ws + 256);             // 128 KB @ 256
  short8* Ap = (short8*)((char*)d_ws + 262144);          // 256 KB @ 256K

  const int pblocks = (N + 255) / 256;
  prep_kernel<<<dim3(1 + pblocks), 256, 0, stream>>>(p, N, out, P4, mmx, Ap);

  const int sblocks = (M + SPBLK - 1) / SPBLK;           // 256
  dist_kernel<<<dim3(sblocks), dim3(64 * WV), 0, stream>>>(u, M, N, P4, mmx,
                                                           Ap, out);
}

// Round 15
// 27.451 us; speedup vs baseline: 1.6163x; 1.6163x over previous
//
#include <hip/hip_runtime.h>
#include <hip/hip_bf16.h>
#include <float.h>

// RandomAugment: out = concat(p, where(dist(s, p) > 1, s, 0))
//   d2[m][n] = s2[m] + p2[n] - 2 s_m . p_n   via mfma_f32_32x32x16_bf16
// K=16 carries a 2-term bf16 hi/lo split (only s_lo*p_lo dropped, err<=1.5e-3);
// borderline samples (|d2_q-1|<=1e-2) get an exact in-block rescan with the
// bit-validated fmaf chain -> mask decisions match numpy exactly.
//
// R15: batch-issue/batch-consume. R14's rotating prefetch regressed (spill/
// serialization from conditional refill + rotation). Here: 8 NAMED tile regs,
// literal addresses, loads issued back-to-back then 8 consume groups -> the
// compiler emits counted vmcnt(7..0) drains; load-0 latency paid once per
// half-pass, loads 1-7 stream behind the ~100cy consume groups. Two half-
// passes of 8 tiles each (TPW=16). No dynamic indexing anywhere (rule #20).

typedef __attribute__((ext_vector_type(8))) short short8;
typedef __attribute__((ext_vector_type(16))) float float16;

constexpr float MARGIN = 1e-2f;
constexpr int WV = 16;     // waves per dist block (1024 threads)
constexpr int SPBLK = 128; // samples per block (4 B fragments)

__device__ __forceinline__ unsigned short f2bf(float f) {
  unsigned u = __float_as_uint(f);
  unsigned r = (u + 0x7FFFu + ((u >> 16) & 1u)) >> 16;  // RNE
  return (unsigned short)r;
}
__device__ __forceinline__ float bf2f(unsigned short b) {
  return __uint_as_float(((unsigned)b) << 16);
}

__global__ __launch_bounds__(256) void prep_kernel(
    const float* __restrict__ p, int N,
    float* __restrict__ out, float4* __restrict__ P4, float* __restrict__ mmx,
    short8* __restrict__ Ap) {
  const int tid = threadIdx.x;
  if (blockIdx.x == 0) {
    float mn0 = FLT_MAX, mn1 = FLT_MAX, mn2 = FLT_MAX;
    float mx0 = -FLT_MAX, mx1 = -FLT_MAX, mx2 = -FLT_MAX;
    for (int j = tid; j < N; j += 256) {
      float x = p[3 * j], y = p[3 * j + 1], z = p[3 * j + 2];
      mn0 = fminf(mn0, x); mx0 = fmaxf(mx0, x);
      mn1 = fminf(mn1, y); mx1 = fmaxf(mx1, y);
      mn2 = fminf(mn2, z); mx2 = fmaxf(mx2, z);
    }
    for (int off = 32; off; off >>= 1) {
      mn0 = fminf(mn0, __shfl_xor(mn0, off));
      mn1 = fminf(mn1, __shfl_xor(mn1, off));
      mn2 = fminf(mn2, __shfl_xor(mn2, off));
      mx0 = fmaxf(mx0, __shfl_xor(mx0, off));
      mx1 = fmaxf(mx1, __shfl_xor(mx1, off));
      mx2 = fmaxf(mx2, __shfl_xor(mx2, off));
    }
    __shared__ float smn[4][3], smx[4][3];
    const int w = tid >> 6;
    if ((tid & 63) == 0) {
      smn[w][0] = mn0; smn[w][1] = mn1; smn[w][2] = mn2;
      smx[w][0] = mx0; smx[w][1] = mx1; smx[w][2] = mx2;
    }
    __syncthreads();
    if (tid == 0) {
      for (int k = 0; k < 3; ++k) {
        float a = smn[0][k], b = smx[0][k];
        for (int w2 = 1; w2 < 4; ++w2) {
          a = fminf(a, smn[w2][k]);
          b = fmaxf(b, smx[w2][k]);
        }
        mmx[k] = a;       // mm
        mmx[3 + k] = b;   // mx
      }
    }
  } else {
    const int j = (blockIdx.x - 1) * 256 + tid;   // one point per thread
    if (j < N) {
      float x = p[3 * j], y = p[3 * j + 1], z = p[3 * j + 2];
      out[3 * j] = x; out[3 * j + 1] = y; out[3 * j + 2] = z;
      float n2 = __fadd_rn(__fadd_rn(__fmul_rn(x, x), __fmul_rn(y, y)),
                           __fmul_rn(z, z));
      P4[j] = make_float4(x, y, z, n2);

      // ---- A-fragment packing (split bf16) ----
      unsigned short hx = f2bf(x), hy = f2bf(y), hz = f2bf(z);
      unsigned short lx = f2bf(x - bf2f(hx));
      unsigned short ly = f2bf(y - bf2f(hy));
      unsigned short lz = f2bf(z - bf2f(hz));
      unsigned short p2h = f2bf(n2);
      unsigned short p2l = f2bf(n2 - bf2f(p2h));
      const unsigned short one = 0x3F80;

      const int tile = j >> 5, r = j & 31;
      short8 h0, h1;
      // lanes 0-31 (k0-7): [p_hi x3, p_lo x3, p_hi x,y]
      h0[0] = (short)hx; h0[1] = (short)hy; h0[2] = (short)hz;
      h0[3] = (short)lx; h0[4] = (short)ly; h0[5] = (short)lz;
      h0[6] = (short)hx; h0[7] = (short)hy;
      // lanes 32-63 (k8-15): [p_hi z, 1, 1, p2_h, p2_l, 0, 0, 0]
      h1[0] = (short)hz; h1[1] = (short)one; h1[2] = (short)one;
      h1[3] = (short)p2h; h1[4] = (short)p2l;
      h1[5] = 0; h1[6] = 0; h1[7] = 0;
      Ap[tile * 64 + r] = h0;
      Ap[tile * 64 + 32 + r] = h1;
    }
  }
}

// fold 16 C values + running min via min3-shaped nests (clang -> v_min3_f32)
__device__ __forceinline__ float min16r(float16 c, float run) {
  float t0 = fminf(fminf(c[0], c[1]), c[2]);
  float t1 = fminf(fminf(c[3], c[4]), c[5]);
  float t2 = fminf(fminf(c[6], c[7]), c[8]);
  float t3 = fminf(fminf(c[9], c[10]), c[11]);
  float t4 = fminf(fminf(c[12], c[13]), c[14]);
  float u0 = fminf(fminf(t0, t1), c[15]);
  float u1 = fminf(fminf(t2, t3), t4);
  return fminf(fminf(run, u0), u1);
}

__global__ __launch_bounds__(64 * WV, 4) void dist_kernel(
    const float* __restrict__ u, int M, int N,
    const float4* __restrict__ P4, const float* __restrict__ mmx,
    const short8* __restrict__ Ap, float* __restrict__ out) {
  const int tid = threadIdx.x;
  const int lane = tid & 63;
  const int wv = tid >> 6;
  const int sbase = blockIdx.x * SPBLK;

  const float mm0 = mmx[0], mm1 = mmx[1], mm2 = mmx[2];
  const float r0v = __fsub_rn(mmx[3], mm0);
  const float r1v = __fsub_rn(mmx[4], mm1);
  const float r2v = __fsub_rn(mmx[5], mm2);

  // ---- build 4 B fragments (samples sbase+f*32+(lane&31)) ----
  short8 B[4];
  const bool hi = lane >= 32;
#pragma unroll
  for (int f = 0; f < 4; ++f) {
    int sc = min(sbase + f * 32 + (lane & 31), M - 1);
    float sx = __fadd_rn(__fmul_rn(u[3 * sc], r0v), mm0);
    float sy = __fadd_rn(__fmul_rn(u[3 * sc + 1], r1v), mm1);
    float sz = __fadd_rn(__fmul_rn(u[3 * sc + 2], r2v), mm2);
    float s2 = __fadd_rn(
        __fadd_rn(__fmul_rn(sx, sx), __fmul_rn(sy, sy)), __fmul_rn(sz, sz));
    unsigned short shx = f2bf(sx), shy = f2bf(sy), shz = f2bf(sz);
    unsigned short slx = f2bf(sx - bf2f(shx));
    unsigned short sly = f2bf(sy - bf2f(shy));
    unsigned short slz = f2bf(sz - bf2f(shz));
    unsigned short n2shx = f2bf(-2.0f * bf2f(shx));
    unsigned short n2shy = f2bf(-2.0f * bf2f(shy));
    unsigned short n2shz = f2bf(-2.0f * bf2f(shz));
    unsigned short n2slx = f2bf(-2.0f * bf2f(slx));
    unsigned short n2sly = f2bf(-2.0f * bf2f(sly));
    unsigned short n2slz = f2bf(-2.0f * bf2f(slz));
    unsigned short s2h = f2bf(s2);
    unsigned short s2l = f2bf(s2 - bf2f(s2h));
    const unsigned short one = 0x3F80;
    short8 b;
    b[0] = (short)(hi ? n2slz : n2shx);
    b[1] = (short)(hi ? s2h : n2shy);
    b[2] = (short)(hi ? s2l : n2shz);
    b[3] = (short)(hi ? one : n2shx);
    b[4] = (short)(hi ? one : n2shy);
    b[5] = (short)(hi ? 0 : n2shz);
    b[6] = (short)(hi ? 0 : n2slx);
    b[7] = (short)(hi ? 0 : n2sly);
    B[f] = b;
  }

  // ---- MFMA: 2 half-passes of {8 batch loads -> 8 consume groups} ----
  const int NT = N >> 5;            // 256 tiles
  const int TPW = NT / WV;          // 16 tiles per wave (= 2 x 8)
  const short8* __restrict__ ap = Ap + (wv * TPW) * 64 + lane;
  const float16 cz = (float16)0.0f;

  float run0 = FLT_MAX, run1 = FLT_MAX, run2 = FLT_MAX, run3 = FLT_MAX;

  short8 t0, t1, t2, t3, t4, t5, t6, t7;

#define CONSUME(areg)                                                          \
  {                                                                            \
    float16 c0 = __builtin_amdgcn_mfma_f32_32x32x16_bf16(areg, B[0], cz, 0, 0, 0); \
    run0 = min16r(c0, run0);                                                   \
    float16 c1 = __builtin_amdgcn_mfma_f32_32x32x16_bf16(areg, B[1], cz, 0, 0, 0); \
    run1 = min16r(c1, run1);                                                   \
    float16 c2 = __builtin_amdgcn_mfma_f32_32x32x16_bf16(areg, B[2], cz, 0, 0, 0); \
    run2 = min16r(c2, run2);                                                   \
    float16 c3 = __builtin_amdgcn_mfma_f32_32x32x16_bf16(areg, B[3], cz, 0, 0, 0); \
    run3 = min16r(c3, run3);                                                   \
  }

  // half-pass 1: tiles 0..7 (all literal offsets; loads issue back-to-back)
  t0 = ap[0 * 64]; t1 = ap[1 * 64]; t2 = ap[2 * 64]; t3 = ap[3 * 64];
  t4 = ap[4 * 64]; t5 = ap[5 * 64]; t6 = ap[6 * 64]; t7 = ap[7 * 64];
  CONSUME(t0); CONSUME(t1); CONSUME(t2); CONSUME(t3);
  CONSUME(t4); CONSUME(t5); CONSUME(t6); CONSUME(t7);

  // half-pass 2: tiles 8..15
  t0 = ap[8 * 64];  t1 = ap[9 * 64];  t2 = ap[10 * 64]; t3 = ap[11 * 64];
  t4 = ap[12 * 64]; t5 = ap[13 * 64]; t6 = ap[14 * 64]; t7 = ap[15 * 64];
  CONSUME(t0); CONSUME(t1); CONSUME(t2); CONSUME(t3);
  CONSUME(t4); CONSUME(t5); CONSUME(t6); CONSUME(t7);
#undef CONSUME

  // rows fully covered by reg-fold + xor32 (layout-proof)
  run0 = fminf(run0, __shfl_xor(run0, 32));
  run1 = fminf(run1, __shfl_xor(run1, 32));
  run2 = fminf(run2, __shfl_xor(run2, 32));
  run3 = fminf(run3, __shfl_xor(run3, 32));

  __shared__ float part[WV][SPBLK];
  {
    const int l31 = lane & 31;
    part[wv][0 * 32 + l31] = run0;   // both half-waves write identical values
    part[wv][1 * 32 + l31] = run1;
    part[wv][2 * 32 + l31] = run2;
    part[wv][3 * 32 + l31] = run3;
  }

  __shared__ float s_sx[SPBLK], s_sy[SPBLK], s_sz[SPBLK], s_s2[SPBLK];
  __shared__ int s_keep[SPBLK];
  __shared__ int s_bl[SPBLK];
  __shared__ int s_nbl;
  __shared__ float s_red[WV];
  if (tid == 0) s_nbl = 0;
  __syncthreads();

  // ---- per-sample: approx decision + borderline detection ----
  if (tid < SPBLK && sbase + tid < M) {
    int sc = sbase + tid;
    float sx = __fadd_rn(__fmul_rn(u[3 * sc], r0v), mm0);
    float sy = __fadd_rn(__fmul_rn(u[3 * sc + 1], r1v), mm1);
    float sz = __fadd_rn(__fmul_rn(u[3 * sc + 2], r2v), mm2);
    float s2 = __fadd_rn(
        __fadd_rn(__fmul_rn(sx, sx), __fmul_rn(sy, sy)), __fmul_rn(sz, sz));
    s_sx[tid] = sx; s_sy[tid] = sy; s_sz[tid] = sz; s_s2[tid] = s2;
    float q = part[0][tid];
#pragma unroll
    for (int w = 1; w < WV; ++w) q = fminf(q, part[w][tid]);
    s_keep[tid] = q > 1.0f;
    if (fabsf(q - 1.0f) <= MARGIN) {
      int idx = atomicAdd(&s_nbl, 1);
      s_bl[idx] = tid;
    }
  }
  __syncthreads();

  // ---- exact rescan of borderline samples (bit-validated fmaf chain) ----
  const int nbl = s_nbl;
  for (int i = 0; i < nbl; ++i) {
    const int t = s_bl[i];
    const float m2x = -2.0f * s_sx[t];
    const float m2y = -2.0f * s_sy[t];
    const float m2z = -2.0f * s_sz[t];
    float dm = FLT_MAX;
    for (int j = tid; j < N; j += 64 * WV) {
      float4 qq = P4[j];
      float tt = fmaf(m2x, qq.x, fmaf(m2y, qq.y, fmaf(m2z, qq.z, qq.w)));
      dm = fminf(dm, tt);
    }
    dm = fminf(dm, __shfl_xor(dm, 1));
    dm = fminf(dm, __shfl_xor(dm, 2));
    dm = fminf(dm, __shfl_xor(dm, 4));
    dm = fminf(dm, __shfl_xor(dm, 8));
    dm = fminf(dm, __shfl_xor(dm, 16));
    dm = fminf(dm, __shfl_xor(dm, 32));
    if (lane == 0) s_red[wv] = dm;
    __syncthreads();
    if (tid == 0) {
      float d = s_red[0];
#pragma unroll
      for (int w = 1; w < WV; ++w) d = fminf(d, s_red[w]);
      float d2 = __fadd_rn(s_s2[t], d);
      float dist = sqrtf(fmaxf(d2, 0.0f));
      s_keep[t] = dist > 1.0f;
    }
    __syncthreads();
  }

  // ---- write masked samples ----
  if (tid < SPBLK && sbase + tid < M) {
    const bool keep = s_keep[tid] != 0;
    float* o = out + (size_t)(N + sbase + tid) * 3;
    o[0] = keep ? s_sx[tid] : 0.0f;
    o[1] = keep ? s_sy[tid] : 0.0f;
    o[2] = keep ? s_sz[tid] : 0.0f;
  }
}

extern "C" void kernel_launch(void* const* d_in, const int* in_sizes, int n_in,
                              void* d_out, int out_size, void* d_ws, size_t ws_size,
                              hipStream_t stream) {
  const float* p = (const float*)d_in[0];
  const float* u = (const float*)d_in[1];
  const int N = in_sizes[0] / 3;   // 8192
  const int M = in_sizes[1] / 3;   // 32768
  float* out = (float*)d_out;

  float* mmx = (float*)d_ws;                             // 6 floats @ 0
  float4* P4 = (float4*)((char*)d_ws + 256);             // 128 KB @ 256
  short8* Ap = (short8*)((char*)d_ws + 262144);          // 256 KB @ 256K

  const int pblocks = (N + 255) / 256;
  prep_kernel<<<dim3(1 + pblocks), 256, 0, stream>>>(p, N, out, P4, mmx, Ap);

  const int sblocks = (M + SPBLK - 1) / SPBLK;           // 256
  dist_kernel<<<dim3(sblocks), dim3(64 * WV), 0, stream>>>(u, M, N, P4, mmx,
                                                           Ap, out);
}

// Round 16
// 26.354 us; speedup vs baseline: 1.6836x; 1.0416x over previous
//
#include <hip/hip_runtime.h>
#include <hip/hip_bf16.h>
#include <float.h>

// RandomAugment: out = concat(p, where(dist(s, p) > 1, s, 0))
//   d2[m][n] = s2[m] + p2[n] - 2 s_m . p_n   via mfma_f32_32x32x16_bf16
// K=16 carries a 2-term bf16 hi/lo split (only s_lo*p_lo dropped, err<=1.5e-3);
// borderline samples (|d2_q-1|<=1e-2) get an exact in-block rescan with the
// bit-validated fmaf chain -> mask decisions match numpy exactly.
//
// R16: R15 dist body (best: 27.45us) + fast prep. Non-dist time ~10-11us of
// the total; prep's 256-thread x 32-iter min/max was the serial head. Now
// 9 blocks x 1024 threads: block0 min/max (8 pts/thread, 16-wave butterfly),
// blocks 1-8 pack one point/thread. dist unchanged (protect the win).

typedef __attribute__((ext_vector_type(8))) short short8;
typedef __attribute__((ext_vector_type(16))) float float16;

constexpr float MARGIN = 1e-2f;
constexpr int WV = 16;     // waves per dist block (1024 threads)
constexpr int SPBLK = 128; // samples per block (4 B fragments)

__device__ __forceinline__ unsigned short f2bf(float f) {
  unsigned u = __float_as_uint(f);
  unsigned r = (u + 0x7FFFu + ((u >> 16) & 1u)) >> 16;  // RNE
  return (unsigned short)r;
}
__device__ __forceinline__ float bf2f(unsigned short b) {
  return __uint_as_float(((unsigned)b) << 16);
}

__global__ __launch_bounds__(1024) void prep_kernel(
    const float* __restrict__ p, int N,
    float* __restrict__ out, float4* __restrict__ P4, float* __restrict__ mmx,
    short8* __restrict__ Ap) {
  const int tid = threadIdx.x;
  if (blockIdx.x == 0) {
    // 1024-thread min/max: 8 points per thread
    float mn0 = FLT_MAX, mn1 = FLT_MAX, mn2 = FLT_MAX;
    float mx0 = -FLT_MAX, mx1 = -FLT_MAX, mx2 = -FLT_MAX;
    for (int j = tid; j < N; j += 1024) {
      float x = p[3 * j], y = p[3 * j + 1], z = p[3 * j + 2];
      mn0 = fminf(mn0, x); mx0 = fmaxf(mx0, x);
      mn1 = fminf(mn1, y); mx1 = fmaxf(mx1, y);
      mn2 = fminf(mn2, z); mx2 = fmaxf(mx2, z);
    }
    for (int off = 32; off; off >>= 1) {
      mn0 = fminf(mn0, __shfl_xor(mn0, off));
      mn1 = fminf(mn1, __shfl_xor(mn1, off));
      mn2 = fminf(mn2, __shfl_xor(mn2, off));
      mx0 = fmaxf(mx0, __shfl_xor(mx0, off));
      mx1 = fmaxf(mx1, __shfl_xor(mx1, off));
      mx2 = fmaxf(mx2, __shfl_xor(mx2, off));
    }
    __shared__ float smn[16][3], smx[16][3];
    const int w = tid >> 6;
    if ((tid & 63) == 0) {
      smn[w][0] = mn0; smn[w][1] = mn1; smn[w][2] = mn2;
      smx[w][0] = mx0; smx[w][1] = mx1; smx[w][2] = mx2;
    }
    __syncthreads();
    if (tid == 0) {
      for (int k = 0; k < 3; ++k) {
        float a = smn[0][k], b = smx[0][k];
        for (int w2 = 1; w2 < 16; ++w2) {
          a = fminf(a, smn[w2][k]);
          b = fmaxf(b, smx[w2][k]);
        }
        mmx[k] = a;       // mm
        mmx[3 + k] = b;   // mx
      }
    }
  } else {
    const int j = (blockIdx.x - 1) * 1024 + tid;   // one point per thread
    if (j < N) {
      float x = p[3 * j], y = p[3 * j + 1], z = p[3 * j + 2];
      out[3 * j] = x; out[3 * j + 1] = y; out[3 * j + 2] = z;
      float n2 = __fadd_rn(__fadd_rn(__fmul_rn(x, x), __fmul_rn(y, y)),
                           __fmul_rn(z, z));
      P4[j] = make_float4(x, y, z, n2);

      // ---- A-fragment packing (split bf16) ----
      unsigned short hx = f2bf(x), hy = f2bf(y), hz = f2bf(z);
      unsigned short lx = f2bf(x - bf2f(hx));
      unsigned short ly = f2bf(y - bf2f(hy));
      unsigned short lz = f2bf(z - bf2f(hz));
      unsigned short p2h = f2bf(n2);
      unsigned short p2l = f2bf(n2 - bf2f(p2h));
      const unsigned short one = 0x3F80;

      const int tile = j >> 5, r = j & 31;
      short8 h0, h1;
      // lanes 0-31 (k0-7): [p_hi x3, p_lo x3, p_hi x,y]
      h0[0] = (short)hx; h0[1] = (short)hy; h0[2] = (short)hz;
      h0[3] = (short)lx; h0[4] = (short)ly; h0[5] = (short)lz;
      h0[6] = (short)hx; h0[7] = (short)hy;
      // lanes 32-63 (k8-15): [p_hi z, 1, 1, p2_h, p2_l, 0, 0, 0]
      h1[0] = (short)hz; h1[1] = (short)one; h1[2] = (short)one;
      h1[3] = (short)p2h; h1[4] = (short)p2l;
      h1[5] = 0; h1[6] = 0; h1[7] = 0;
      Ap[tile * 64 + r] = h0;
      Ap[tile * 64 + 32 + r] = h1;
    }
  }
}

// fold 16 C values + running min via min3-shaped nests (clang -> v_min3_f32)
__device__ __forceinline__ float min16r(float16 c, float run) {
  float t0 = fminf(fminf(c[0], c[1]), c[2]);
  float t1 = fminf(fminf(c[3], c[4]), c[5]);
  float t2 = fminf(fminf(c[6], c[7]), c[8]);
  float t3 = fminf(fminf(c[9], c[10]), c[11]);
  float t4 = fminf(fminf(c[12], c[13]), c[14]);
  float u0 = fminf(fminf(t0, t1), c[15]);
  float u1 = fminf(fminf(t2, t3), t4);
  return fminf(fminf(run, u0), u1);
}

__global__ __launch_bounds__(64 * WV, 4) void dist_kernel(
    const float* __restrict__ u, int M, int N,
    const float4* __restrict__ P4, const float* __restrict__ mmx,
    const short8* __restrict__ Ap, float* __restrict__ out) {
  const int tid = threadIdx.x;
  const int lane = tid & 63;
  const int wv = tid >> 6;
  const int sbase = blockIdx.x * SPBLK;

  const float mm0 = mmx[0], mm1 = mmx[1], mm2 = mmx[2];
  const float r0v = __fsub_rn(mmx[3], mm0);
  const float r1v = __fsub_rn(mmx[4], mm1);
  const float r2v = __fsub_rn(mmx[5], mm2);

  // ---- build 4 B fragments (samples sbase+f*32+(lane&31)) ----
  short8 B[4];
  const bool hi = lane >= 32;
#pragma unroll
  for (int f = 0; f < 4; ++f) {
    int sc = min(sbase + f * 32 + (lane & 31), M - 1);
    float sx = __fadd_rn(__fmul_rn(u[3 * sc], r0v), mm0);
    float sy = __fadd_rn(__fmul_rn(u[3 * sc + 1], r1v), mm1);
    float sz = __fadd_rn(__fmul_rn(u[3 * sc + 2], r2v), mm2);
    float s2 = __fadd_rn(
        __fadd_rn(__fmul_rn(sx, sx), __fmul_rn(sy, sy)), __fmul_rn(sz, sz));
    unsigned short shx = f2bf(sx), shy = f2bf(sy), shz = f2bf(sz);
    unsigned short slx = f2bf(sx - bf2f(shx));
    unsigned short sly = f2bf(sy - bf2f(shy));
    unsigned short slz = f2bf(sz - bf2f(shz));
    unsigned short n2shx = f2bf(-2.0f * bf2f(shx));
    unsigned short n2shy = f2bf(-2.0f * bf2f(shy));
    unsigned short n2shz = f2bf(-2.0f * bf2f(shz));
    unsigned short n2slx = f2bf(-2.0f * bf2f(slx));
    unsigned short n2sly = f2bf(-2.0f * bf2f(sly));
    unsigned short n2slz = f2bf(-2.0f * bf2f(slz));
    unsigned short s2h = f2bf(s2);
    unsigned short s2l = f2bf(s2 - bf2f(s2h));
    const unsigned short one = 0x3F80;
    short8 b;
    b[0] = (short)(hi ? n2slz : n2shx);
    b[1] = (short)(hi ? s2h : n2shy);
    b[2] = (short)(hi ? s2l : n2shz);
    b[3] = (short)(hi ? one : n2shx);
    b[4] = (short)(hi ? one : n2shy);
    b[5] = (short)(hi ? 0 : n2shz);
    b[6] = (short)(hi ? 0 : n2slx);
    b[7] = (short)(hi ? 0 : n2sly);
    B[f] = b;
  }

  // ---- MFMA: 2 half-passes of {8 batch loads -> 8 consume groups} ----
  const int NT = N >> 5;            // 256 tiles
  const int TPW = NT / WV;          // 16 tiles per wave (= 2 x 8)
  const short8* __restrict__ ap = Ap + (wv * TPW) * 64 + lane;
  const float16 cz = (float16)0.0f;

  float run0 = FLT_MAX, run1 = FLT_MAX, run2 = FLT_MAX, run3 = FLT_MAX;

  short8 t0, t1, t2, t3, t4, t5, t6, t7;

#define CONSUME(areg)                                                          \
  {                                                                            \
    float16 c0 = __builtin_amdgcn_mfma_f32_32x32x16_bf16(areg, B[0], cz, 0, 0, 0); \
    run0 = min16r(c0, run0);                                                   \
    float16 c1 = __builtin_amdgcn_mfma_f32_32x32x16_bf16(areg, B[1], cz, 0, 0, 0); \
    run1 = min16r(c1, run1);                                                   \
    float16 c2 = __builtin_amdgcn_mfma_f32_32x32x16_bf16(areg, B[2], cz, 0, 0, 0); \
    run2 = min16r(c2, run2);                                                   \
    float16 c3 = __builtin_amdgcn_mfma_f32_32x32x16_bf16(areg, B[3], cz, 0, 0, 0); \
    run3 = min16r(c3, run3);                                                   \
  }

  // half-pass 1: tiles 0..7 (all literal offsets; loads issue back-to-back)
  t0 = ap[0 * 64]; t1 = ap[1 * 64]; t2 = ap[2 * 64]; t3 = ap[3 * 64];
  t4 = ap[4 * 64]; t5 = ap[5 * 64]; t6 = ap[6 * 64]; t7 = ap[7 * 64];
  CONSUME(t0); CONSUME(t1); CONSUME(t2); CONSUME(t3);
  CONSUME(t4); CONSUME(t5); CONSUME(t6); CONSUME(t7);

  // half-pass 2: tiles 8..15
  t0 = ap[8 * 64];  t1 = ap[9 * 64];  t2 = ap[10 * 64]; t3 = ap[11 * 64];
  t4 = ap[12 * 64]; t5 = ap[13 * 64]; t6 = ap[14 * 64]; t7 = ap[15 * 64];
  CONSUME(t0); CONSUME(t1); CONSUME(t2); CONSUME(t3);
  CONSUME(t4); CONSUME(t5); CONSUME(t6); CONSUME(t7);
#undef CONSUME

  // rows fully covered by reg-fold + xor32 (layout-proof)
  run0 = fminf(run0, __shfl_xor(run0, 32));
  run1 = fminf(run1, __shfl_xor(run1, 32));
  run2 = fminf(run2, __shfl_xor(run2, 32));
  run3 = fminf(run3, __shfl_xor(run3, 32));

  __shared__ float part[WV][SPBLK];
  {
    const int l31 = lane & 31;
    part[wv][0 * 32 + l31] = run0;   // both half-waves write identical values
    part[wv][1 * 32 + l31] = run1;
    part[wv][2 * 32 + l31] = run2;
    part[wv][3 * 32 + l31] = run3;
  }

  __shared__ float s_sx[SPBLK], s_sy[SPBLK], s_sz[SPBLK], s_s2[SPBLK];
  __shared__ int s_keep[SPBLK];
  __shared__ int s_bl[SPBLK];
  __shared__ int s_nbl;
  __shared__ float s_red[WV];
  if (tid == 0) s_nbl = 0;
  __syncthreads();

  // ---- per-sample: approx decision + borderline detection ----
  if (tid < SPBLK && sbase + tid < M) {
    int sc = sbase + tid;
    float sx = __fadd_rn(__fmul_rn(u[3 * sc], r0v), mm0);
    float sy = __fadd_rn(__fmul_rn(u[3 * sc + 1], r1v), mm1);
    float sz = __fadd_rn(__fmul_rn(u[3 * sc + 2], r2v), mm2);
    float s2 = __fadd_rn(
        __fadd_rn(__fmul_rn(sx, sx), __fmul_rn(sy, sy)), __fmul_rn(sz, sz));
    s_sx[tid] = sx; s_sy[tid] = sy; s_sz[tid] = sz; s_s2[tid] = s2;
    float q = part[0][tid];
#pragma unroll
    for (int w = 1; w < WV; ++w) q = fminf(q, part[w][tid]);
    s_keep[tid] = q > 1.0f;
    if (fabsf(q - 1.0f) <= MARGIN) {
      int idx = atomicAdd(&s_nbl, 1);
      s_bl[idx] = tid;
    }
  }
  __syncthreads();

  // ---- exact rescan of borderline samples (bit-validated fmaf chain) ----
  const int nbl = s_nbl;
  for (int i = 0; i < nbl; ++i) {
    const int t = s_bl[i];
    const float m2x = -2.0f * s_sx[t];
    const float m2y = -2.0f * s_sy[t];
    const float m2z = -2.0f * s_sz[t];
    float dm = FLT_MAX;
    for (int j = tid; j < N; j += 64 * WV) {
      float4 qq = P4[j];
      float tt = fmaf(m2x, qq.x, fmaf(m2y, qq.y, fmaf(m2z, qq.z, qq.w)));
      dm = fminf(dm, tt);
    }
    dm = fminf(dm, __shfl_xor(dm, 1));
    dm = fminf(dm, __shfl_xor(dm, 2));
    dm = fminf(dm, __shfl_xor(dm, 4));
    dm = fminf(dm, __shfl_xor(dm, 8));
    dm = fminf(dm, __shfl_xor(dm, 16));
    dm = fminf(dm, __shfl_xor(dm, 32));
    if (lane == 0) s_red[wv] = dm;
    __syncthreads();
    if (tid == 0) {
      float d = s_red[0];
#pragma unroll
      for (int w = 1; w < WV; ++w) d = fminf(d, s_red[w]);
      float d2 = __fadd_rn(s_s2[t], d);
      float dist = sqrtf(fmaxf(d2, 0.0f));
      s_keep[t] = dist > 1.0f;
    }
    __syncthreads();
  }

  // ---- write masked samples ----
  if (tid < SPBLK && sbase + tid < M) {
    const bool keep = s_keep[tid] != 0;
    float* o = out + (size_t)(N + sbase + tid) * 3;
    o[0] = keep ? s_sx[tid] : 0.0f;
    o[1] = keep ? s_sy[tid] : 0.0f;
    o[2] = keep ? s_sz[tid] : 0.0f;
  }
}

extern "C" void kernel_launch(void* const* d_in, const int* in_sizes, int n_in,
                              void* d_out, int out_size, void* d_ws, size_t ws_size,
                              hipStream_t stream) {
  const float* p = (const float*)d_in[0];
  const float* u = (const float*)d_in[1];
  const int N = in_sizes[0] / 3;   // 8192
  const int M = in_sizes[1] / 3;   // 32768
  float* out = (float*)d_out;

  float* mmx = (float*)d_ws;                             // 6 floats @ 0
  float4* P4 = (float4*)((char*)d_ws + 256);             // 128 KB @ 256
  short8* Ap = (short8*)((char*)d_ws + 262144);          // 256 KB @ 256K

  const int pblocks = (N + 1023) / 1024;                 // 8
  prep_kernel<<<dim3(1 + pblocks), 1024, 0, stream>>>(p, N, out, P4, mmx, Ap);

  const int sblocks = (M + SPBLK - 1) / SPBLK;           // 256
  dist_kernel<<<dim3(sblocks), dim3(64 * WV), 0, stream>>>(u, M, N, P4, mmx,
                                                           Ap, out);
}